// Round 8
// baseline (16256.943 us; speedup 1.0000x reference)
//
#include <hip/hip_runtime.h>
#include <cstddef>
#include <cstdint>

#define T_STEPS 256
#define BATCH   512
#define NIN     128
#define NHID    1024
#define GRID_WGS 512

typedef _Float16 half8  __attribute__((ext_vector_type(8)));
typedef float    float4v __attribute__((ext_vector_type(4)));

__device__ __forceinline__ float sigmoid_f(float x) { return 1.0f / (1.0f + __expf(-x)); }
__device__ __forceinline__ float tanh_f(float x) {
    float ax = fabsf(x);
    float t  = __expf(-2.0f * ax);
    float r  = (1.0f - t) / (1.0f + t);
    return copysignf(r, x);
}

// ---------------------------------------------------------------------------
// Grid barrier (agent scope).  Monotonic counter + generation flag.
// __threadfence() supplies release (buffer_wbl2) / acquire (buffer_inv) for
// cross-XCD visibility of plain stores.  Bounded spin -> fail, not hang.
// ---------------------------------------------------------------------------
__device__ __forceinline__ void grid_barrier(uint32_t* cnt, uint32_t* gen,
                                             uint32_t target_gen) {
    __syncthreads();
    if (threadIdx.x == 0) {
        __threadfence();                       // release prior writes to LLC
        uint32_t old = __hip_atomic_fetch_add(cnt, 1u, __ATOMIC_RELAXED,
                                              __HIP_MEMORY_SCOPE_AGENT);
        if (old == target_gen * GRID_WGS - 1)
            __hip_atomic_store(gen, target_gen, __ATOMIC_RELAXED,
                               __HIP_MEMORY_SCOPE_AGENT);
        uint32_t spins = 0;
        while (__hip_atomic_load(gen, __ATOMIC_RELAXED,
                                 __HIP_MEMORY_SCOPE_AGENT) < target_gen) {
            __builtin_amdgcn_s_sleep(8);
            if (++spins > 20000000u) break;    // ~4s deadlock bailout
        }
        __threadfence();                       // acquire side
    }
    __syncthreads();
}

// ---------------------------------------------------------------------------
// Fragment layouts (16x16x32 f16 MFMA):
//   frag tile (16 rows x 32 k) = 1KB: halves index lane*8 + j,
//   value = A[r = lane&15][k = (lane>>4)*8 + j]
// Activations (plain fp16): [mtile 32][ktile 32][512 halves]   (1 MB)
// Weights (fp16 hi/lo):     [p 2][ub 64][gate 4][ktile 64][512] (32 MB)
// c arrays (fp32):          [mtile 32][ub 64][lane 64][4 floats] (2 MB)
// 2-product scheme: z = A*(Bh+Bl); weights fp32-exact, act err ~2^-11 fresh
// per step (non-amplifying).
// ---------------------------------------------------------------------------

__global__ __launch_bounds__(256)
void convert_weights(const float* __restrict__ k1, const float* __restrict__ k2,
                     _Float16* __restrict__ wf1, _Float16* __restrict__ wf2)
{
    __shared__ float ws2[32][17];
    const int kt    = blockIdx.x;     // 0..63
    const int ub    = blockIdx.y;     // 0..63
    const int layer = blockIdx.z;
    const float* src = layer ? k2 : k1;
    _Float16*    dst = layer ? wf2 : wf1;
    const int t = threadIdx.x;
    const size_t WPS = (size_t)64 * 4 * 64 * 512;
    for (int g = 0; g < 4; ++g) {
        for (int i = 0; i < 512; i += 256) {
            const int idx = t + i;
            const int kk = idx >> 4, n = idx & 15;
            ws2[kk][n] = src[(size_t)(kt * 32 + kk) * 4096 + g * 1024 + ub * 16 + n];
        }
        __syncthreads();
        const size_t base = (((size_t)ub * 4 + g) * 64 + kt) * 512;
        for (int i = 0; i < 512; i += 256) {
            const int idx = t + i;
            const int lane = idx >> 3, j = idx & 7;
            const float v = ws2[(lane >> 4) * 8 + j][lane & 15];
            const _Float16 hi = (_Float16)v;
            dst[base + idx]       = hi;
            dst[WPS + base + idx] = (_Float16)(v - (float)hi);
        }
        __syncthreads();
    }
}

// ---------------------------------------------------------------------------
// proj appendix: relu(x_t @ W + b) -> frag fp16.  256 roles, 16m x 128u each.
// ---------------------------------------------------------------------------
__device__ __forceinline__ void proj_append(
    const float* __restrict__ x, const float* __restrict__ W,
    const float* __restrict__ bias, _Float16* __restrict__ pf,
    int tstep, int id, char* smem)
{
    float (*ws)[68]  = (float(*)[68])smem;              // [128][68]  34816 B
    float (*xs)[132] = (float(*)[132])(smem + 34816);   // [16][132]   8448 B
    float (*zl)[132] = (float(*)[132])(smem + 43264);   // [16][132]   8448 B

    const int t = threadIdx.x;
    const int mrow = id & 31;
    const int uc   = id >> 5;          // 0..7
    __syncthreads();                   // LDS reuse
    {
        const int m = t >> 4, kq = t & 15;
        const float* xr = x + (size_t)(mrow * 16 + m) * (T_STEPS * NIN)
                            + (size_t)tstep * NIN + kq * 8;
        *(float4v*)&xs[m][kq * 8]     = *(const float4v*)(xr);
        *(float4v*)&xs[m][kq * 8 + 4] = *(const float4v*)(xr + 4);
    }
    for (int h = 0; h < 2; ++h) {
        __syncthreads();
#pragma unroll
        for (int i = 0; i < 8; ++i) {
            const int idx = t + i * 256;
            const int k = idx >> 4, u4 = idx & 15;
            *(float4v*)&ws[k][u4 * 4] =
                *(const float4v*)(W + (size_t)k * NHID + uc * 128 + h * 64 + u4 * 4);
        }
        __syncthreads();
        const int m = t >> 4, u4 = t & 15;
        float4v acc = {0.f, 0.f, 0.f, 0.f};
#pragma unroll 4
        for (int k = 0; k < NIN; ++k) {
            const float a = xs[m][k];
            const float4v wv = *(const float4v*)&ws[k][u4 * 4];
#pragma unroll
            for (int c = 0; c < 4; ++c) acc[c] = fmaf(a, wv[c], acc[c]);
        }
        const float4v bv = *(const float4v*)&bias[uc * 128 + h * 64 + u4 * 4];
#pragma unroll
        for (int c = 0; c < 4; ++c)
            zl[m][h * 64 + u4 * 4 + c] = fmaxf(acc[c] + bv[c], 0.0f);
    }
    __syncthreads();
    const int w = t >> 6, l = t & 63;
    const int m16 = l & 15, jb = (l >> 4) * 8;
    half8 hv;
#pragma unroll
    for (int j = 0; j < 8; ++j)
        hv[j] = (_Float16)zl[m16][w * 32 + jb + j];
    const size_t off = ((size_t)mrow * 32 + (uc * 4 + w)) * 512 + l * 8;
    *(half8*)(pf + off) = hv;
}

// ---------------------------------------------------------------------------
// LSTM task body (4 waves = nh x kh).  Wave: 64m x 16u x 4g, K-half 32 kt.
// 2-product (acts fp16, weights hi+lo), TRIPLE-buffered register prefetch
// (distance 2 ~ 1240 cyc > worst-case L2 latency under congestion).
// ---------------------------------------------------------------------------
__device__ __forceinline__ void lstm_body(
    const _Float16* __restrict__ A0, const _Float16* __restrict__ A1,
    const _Float16* __restrict__ Wf, const float* __restrict__ bias,
    const float* __restrict__ c_old, float* __restrict__ c_new,
    _Float16* __restrict__ hout, float* __restrict__ out_f32,
    int id, char* smem)
{
    float (*red)[4096] = (float(*)[4096])smem;           // [2][4096]
    float (*hl)[36]    = (float(*)[36])(smem + 32768);   // [64][36]

    const int tid = threadIdx.x;
    const int w = tid >> 6, l = tid & 63;
    const int nh = w & 1, kh = w >> 1;
    const int xcd = id & 7;
    const int s   = id >> 3;
    const int mgrp = s & 7;
    const int wgu  = xcd * 4 + (s >> 3);
    const int ub   = wgu * 2 + nh;
    const int q = l >> 4, n = l & 15;

    const _Float16* Af = kh ? A1 : A0;
    const size_t WPS = (size_t)64 * 4 * 64 * 512;

    const char* aB[4];
    const char* bB[2][4];
#pragma unroll
    for (int mt = 0; mt < 4; ++mt)
        aB[mt] = (const char*)(Af + (size_t)(mgrp * 4 + mt) * 32 * 512);
#pragma unroll
    for (int p = 0; p < 2; ++p)
#pragma unroll
        for (int g = 0; g < 4; ++g)
            bB[p][g] = (const char*)(Wf + p * WPS + (((size_t)ub * 4 + g) * 64 + kh * 32) * 512);
    const uint32_t lo16 = (uint32_t)l * 16;

    half8 Ab[3][4], Bb[3][2][4];
    float4v acc[4][4];
#pragma unroll
    for (int mt = 0; mt < 4; ++mt)
#pragma unroll
        for (int g = 0; g < 4; ++g)
            acc[mt][g] = (float4v){0.f, 0.f, 0.f, 0.f};

    auto loadbuf = [&](int kt, int buf) {
        const uint32_t off = lo16 + (uint32_t)kt * 1024u;
#pragma unroll
        for (int mt = 0; mt < 4; ++mt)
            Ab[buf][mt] = *(const half8*)(aB[mt] + off);
#pragma unroll
        for (int p = 0; p < 2; ++p)
#pragma unroll
            for (int g = 0; g < 4; ++g)
                Bb[buf][p][g] = *(const half8*)(bB[p][g] + off);
    };
    auto mstep = [&](int buf) {
#pragma unroll
        for (int g = 0; g < 4; ++g)
#pragma unroll
            for (int mt = 0; mt < 4; ++mt)
                acc[mt][g] = __builtin_amdgcn_mfma_f32_16x16x32_f16(Ab[buf][mt], Bb[buf][0][g], acc[mt][g], 0, 0, 0);
#pragma unroll
        for (int g = 0; g < 4; ++g)
#pragma unroll
            for (int mt = 0; mt < 4; ++mt)
                acc[mt][g] = __builtin_amdgcn_mfma_f32_16x16x32_f16(Ab[buf][mt], Bb[buf][1][g], acc[mt][g], 0, 0, 0);
    };

    loadbuf(0, 0);
    loadbuf(1, 1);
    for (int kt = 0; kt < 30; kt += 3) {   // bufs static per position
        loadbuf(kt + 2, 2); mstep(0);
        loadbuf(kt + 3, 0); mstep(1);
        loadbuf(kt + 4, 1); mstep(2);
    }
    mstep(0);   // kt=30
    mstep(1);   // kt=31

    // k-half reduction
    __syncthreads();
    if (kh == 1) {
#pragma unroll
        for (int mt = 0; mt < 4; ++mt)
#pragma unroll
            for (int g = 0; g < 4; ++g)
#pragma unroll
                for (int r = 0; r < 4; ++r)
                    red[nh][((mt * 4 + g) * 4 + r) * 64 + l] = acc[mt][g][r];
    }
    __syncthreads();
    if (kh == 0) {
#pragma unroll
        for (int mt = 0; mt < 4; ++mt)
#pragma unroll
            for (int g = 0; g < 4; ++g)
#pragma unroll
                for (int r = 0; r < 4; ++r)
                    acc[mt][g][r] += red[nh][((mt * 4 + g) * 4 + r) * 64 + l];

        const int unit = ub * 16 + n;
        const float bi = bias[unit];
        const float bj = bias[NHID + unit];
        const float bf = bias[2 * NHID + unit];
        const float bo = bias[3 * NHID + unit];
#pragma unroll
        for (int mt = 0; mt < 4; ++mt) {
            const int mtglob = mgrp * 4 + mt;
            const size_t cbase = ((size_t)mtglob * 64 + ub) * 256 + l * 4;
            const float4v cv = *(const float4v*)(c_old + cbase);
            float4v cn;
            float hn[4];
#pragma unroll
            for (int r = 0; r < 4; ++r) {
                const float zi = acc[mt][0][r] + bi;
                const float zj = acc[mt][1][r] + bj;
                const float zf = acc[mt][2][r] + bf;
                const float zo = acc[mt][3][r] + bo;
                const float c = cv[r] * sigmoid_f(zf + 1.0f) + sigmoid_f(zi) * tanh_f(zj);
                cn[r] = c;
                hn[r] = tanh_f(c) * sigmoid_f(zo);
            }
            *(float4v*)(c_new + cbase) = cn;
#pragma unroll
            for (int r = 0; r < 4; ++r)
                hl[mt * 16 + q * 4 + r][nh * 16 + n] = hn[r];
            if (out_f32) {
#pragma unroll
                for (int r = 0; r < 4; ++r)
                    out_f32[(size_t)(mgrp * 64 + mt * 16 + q * 4 + r) * NHID + unit] = hn[r];
            }
        }
    }
    __syncthreads();
    // frag-out of new h: wave w handles m-tile w
    const int mloc = w * 16 + n;
    const int q8 = q * 8;
    const float4v v0 = *(const float4v*)&hl[mloc][q8];
    const float4v v1 = *(const float4v*)&hl[mloc][q8 + 4];
    half8 hv;
#pragma unroll
    for (int jx = 0; jx < 4; ++jx) {
        hv[jx]     = (_Float16)v0[jx];
        hv[jx + 4] = (_Float16)v1[jx];
    }
    const size_t off = (((size_t)(mgrp * 4 + w)) * 32 + wgu) * 512 + l * 8;
    *(half8*)(hout + off) = hv;
}

// ---------------------------------------------------------------------------
// Persistent kernel: all 258 phases, grid barrier between phases.
// Grid 512 = exactly 2 WG/CU (LDS 61KB -> 2/CU fits; launch_bounds caps VGPR).
//   bid 0..255   : L1(t=p) GEMM + proj(p+1) appendix
//   bid 256..511 : L2(t=p-1) GEMM
// ---------------------------------------------------------------------------
__global__ __launch_bounds__(256, 2)
void persist_kernel(const float* __restrict__ x, const float* __restrict__ W_h,
                    const float* __restrict__ b_h,
                    const _Float16* __restrict__ wf1, const float* __restrict__ b1,
                    const _Float16* __restrict__ wf2, const float* __restrict__ b2,
                    uint8_t* wsb, float* __restrict__ out,
                    uint32_t* barrier_mem)
{
    __shared__ __align__(16) char smem[62464];
    const size_t MB = 1024 * 1024;
    float*    c1f[2] = {(float*)(wsb + 0 * MB),    (float*)(wsb + 6 * MB)};
    _Float16* h1f[2] = {(_Float16*)(wsb + 2 * MB), (_Float16*)(wsb + 8 * MB)};
    float*    c2f[2] = {(float*)(wsb + 9 * MB),    (float*)(wsb + 3 * MB)};
    _Float16* h2f[2] = {(_Float16*)(wsb + 11 * MB),(_Float16*)(wsb + 5 * MB)};
    _Float16* pf[2]  = {(_Float16*)(wsb + 12 * MB), (_Float16*)(wsb + 13 * MB)};
    uint32_t* cnt = barrier_mem;
    uint32_t* gen = barrier_mem + 32;   // separate cachelines

    const int bid = blockIdx.x;

    // pre-phase: proj(0) -> pf[0]
    if (bid < 256) proj_append(x, W_h, b_h, pf[0], 0, bid, smem);
    grid_barrier(cnt, gen, 1u);

    for (int p = 0; p <= 256; ++p) {
        const int pi = p & 1, po = pi ^ 1;
        if (bid < 256) {
            if (p <= 255)
                lstm_body(pf[pi], h1f[pi], wf1, b1, c1f[pi], c1f[po],
                          h1f[po], nullptr, bid, smem);
            if (p + 1 <= 255)
                proj_append(x, W_h, b_h, pf[po], p + 1, bid, smem);
        } else {
            if (p >= 1)
                lstm_body(h1f[pi], h2f[pi], wf2, b2, c2f[pi], c2f[po],
                          h2f[po], (p == 256) ? out : nullptr, bid - 256, smem);
        }
        grid_barrier(cnt, gen, (uint32_t)(p + 2));
    }
}

// ---------------------------------------------------------------------------
extern "C" void kernel_launch(void* const* d_in, const int* in_sizes, int n_in,
                              void* d_out, int out_size, void* d_ws, size_t ws_size,
                              hipStream_t stream)
{
    const float* x   = (const float*)d_in[0];
    const float* W_h = (const float*)d_in[1];
    const float* b_h = (const float*)d_in[2];
    const float* k1  = (const float*)d_in[3];
    const float* b1  = (const float*)d_in[4];
    const float* k2  = (const float*)d_in[5];
    const float* b2  = (const float*)d_in[6];
    float* out = (float*)d_out;

    const size_t MB = 1024 * 1024;
    uint8_t* wsb = (uint8_t*)d_ws;
    _Float16* wf1 = (_Float16*)(wsb + 14 * MB);
    _Float16* wf2 = (_Float16*)(wsb + 46 * MB);          // ends at 78 MB
    uint32_t* barrier_mem = (uint32_t*)(wsb + 78 * MB);  // 4 KB

    // zero: c1f[0](2MB)+h1f[0](1MB) @0..3MB? layout: 0..6MB block covers
    // c1f[0](0-2), h1f[0](2-3), c2f[1](3-5), h2f[1](5-6)  -- first-read bufs
    hipMemsetAsync(wsb, 0, 6 * MB, stream);
    hipMemsetAsync(barrier_mem, 0, 4096, stream);
    convert_weights<<<dim3(64, 64, 2), 256, 0, stream>>>(k1, k2, wf1, wf2);

    persist_kernel<<<GRID_WGS, 256, 0, stream>>>(
        x, W_h, b_h, wf1, b1, wf2, b2, wsb, out, barrier_mem);
}

// Round 9
// 9858.501 us; speedup vs baseline: 1.6490x; 1.6490x over previous
//
#include <hip/hip_runtime.h>
#include <cstddef>
#include <cstdint>

#define T_STEPS 256
#define BATCH   512
#define NIN     128
#define NHID    1024
#define NWGS    256

typedef _Float16 half8  __attribute__((ext_vector_type(8)));
typedef float    float4v __attribute__((ext_vector_type(4)));

__device__ __forceinline__ float sigmoid_f(float x) { return 1.0f / (1.0f + __expf(-x)); }
__device__ __forceinline__ float tanh_f(float x) {
    float ax = fabsf(x);
    float t  = __expf(-2.0f * ax);
    float r  = (1.0f - t) / (1.0f + t);
    return copysignf(r, x);
}

// LDS map (dynamic, 154 KB)
#define WLDS_OFF  0         // 131072 B: weight B-frags [nt 2][kt 64][lane 64][16B]
#define WHF_OFF   131072    // 4096 B:  proj B-frags [kt 4][lane 64][16B]
#define ZS_OFF    135168    // 16384 B: per-wave z scratch (2048 B each)
#define HS_OFF    151552    // 2048 B:  per-wave h scratch (256 B each)
#define BIASG_OFF 153600    // 128 B:   gate bias [g 4][u 8] f32
#define BH_OFF    153728    // 32 B:    proj bias [u 8] f32
#define SMEM_BYTES 153760

// ---------------------------------------------------------------------------
// Grid barrier (agent scope) — proven in R8.
// ---------------------------------------------------------------------------
__device__ __forceinline__ void grid_barrier(uint32_t* cnt, uint32_t* gen,
                                             uint32_t target_gen) {
    __syncthreads();
    if (threadIdx.x == 0) {
        __threadfence();
        uint32_t old = __hip_atomic_fetch_add(cnt, 1u, __ATOMIC_RELAXED,
                                              __HIP_MEMORY_SCOPE_AGENT);
        if (old == target_gen * NWGS - 1)
            __hip_atomic_store(gen, target_gen, __ATOMIC_RELAXED,
                               __HIP_MEMORY_SCOPE_AGENT);
        uint32_t spins = 0;
        while (__hip_atomic_load(gen, __ATOMIC_RELAXED,
                                 __HIP_MEMORY_SCOPE_AGENT) < target_gen) {
            __builtin_amdgcn_s_sleep(8);
            if (++spins > 20000000u) break;
        }
        __threadfence();
    }
    __syncthreads();
}

// ---------------------------------------------------------------------------
// One-time x -> fp16 A-frag conversion.
// xf[t 256][mt 32][kt 4][512 halves]; value = x[mt*16+(lane&15)][t][kt*32+(lane>>4)*8+j]
// Grid (32 mt, 16 tb), 256 thr.
// ---------------------------------------------------------------------------
__global__ __launch_bounds__(256)
void xconv_kernel(const float* __restrict__ x, _Float16* __restrict__ xf)
{
    __shared__ float xs[16][2][128];
    const int mt = blockIdx.x, tb = blockIdx.y;
    const int t = threadIdx.x;
    for (int tl = 0; tl < 8; ++tl) {
        __syncthreads();
#pragma unroll
        for (int i = 0; i < 4; ++i) {
            const int idx = t + i * 256;
            const int m = idx >> 6, rest = idx & 63;
            const int t2 = rest >> 5, k4 = rest & 31;
            float4v v = *(const float4v*)(x +
                ((size_t)(mt * 16 + m) * T_STEPS + (tb * 16 + tl * 2 + t2)) * NIN + k4 * 4);
            *(float4v*)&xs[m][t2][k4 * 4] = v;
        }
        __syncthreads();
#pragma unroll
        for (int i = 0; i < 2; ++i) {
            const int idx = t + i * 256;
            const int t2 = idx >> 8, rest = idx & 255;
            const int kt = rest >> 6, lane = rest & 63;
            half8 hv;
#pragma unroll
            for (int j = 0; j < 8; ++j)
                hv[j] = (_Float16)xs[lane & 15][t2][kt * 32 + (lane >> 4) * 8 + j];
            const int tg = tb * 16 + tl * 2 + t2;
            *(half8*)(xf + (((size_t)tg * 32 + mt) * 4 + kt) * 512 + lane * 8) = hv;
        }
    }
}

// ---------------------------------------------------------------------------
// Persistent kernel.  256 WGs x 512 thr, 1 WG/CU (154 KB LDS).
// WG: layer = bid&1, slice s = bid>>1 (8 units).  Weights fp16 LDS-pinned.
// GEMM: M=512 (8 waves x 4 mt), N=32 (2 nt: cols g*8+u), K=2048 (64 kt).
// c state in VGPRs for the whole sequence.
// A-buffers (frag layout [mt 32][kt 64][512]):
//   A1[par]: low kt = pf(t), high = h1(t-1);  A2[par]: low = h1, high = h2.
// ---------------------------------------------------------------------------
__global__ __launch_bounds__(512, 2)
void persist_kernel(const float* __restrict__ k1, const float* __restrict__ b1,
                    const float* __restrict__ k2, const float* __restrict__ b2,
                    const float* __restrict__ W_h, const float* __restrict__ b_h,
                    const _Float16* __restrict__ xf,
                    uint8_t* wsb, float* __restrict__ out,
                    uint32_t* barrier_mem)
{
    extern __shared__ __align__(16) char smem[];
    const size_t MB = 1024 * 1024;
    _Float16* A1b[2] = {(_Float16*)(wsb + 0 * MB), (_Float16*)(wsb + 2 * MB)};
    _Float16* A2b[2] = {(_Float16*)(wsb + 4 * MB), (_Float16*)(wsb + 6 * MB)};
    uint32_t* cnt = barrier_mem;
    uint32_t* gen = barrier_mem + 32;

    const int tid = threadIdx.x;
    const int w = tid >> 6, lane = tid & 63;
    const int q = lane >> 4, n16 = lane & 15;
    const int bid = blockIdx.x;
    const int layer = bid & 1;
    const int s = bid >> 1;          // 0..127
    const int u0 = s * 8;

    const float* ksrc = layer ? k2 : k1;
    const float* bsrc = layer ? b2 : b1;

    // ---- init: convert weight slice f32 -> fp16 frags in LDS ----
    {
#pragma unroll 1
        for (int i = 0; i < 16; ++i) {
            const int kt = w * 8 + (i & 7);
            const int nt = i >> 3;
            const int colg = (nt * 2 + (n16 >> 3)) * 1024 + u0 + (n16 & 7);
            half8 hv;
#pragma unroll
            for (int j = 0; j < 8; ++j)
                hv[j] = (_Float16)ksrc[(size_t)(kt * 32 + q * 8 + j) * 4096 + colg];
            *(half8*)(smem + WLDS_OFF + (nt * 64 + kt) * 1024 + lane * 16) = hv;
        }
    }
    if (tid < 32)
        ((float*)(smem + BIASG_OFF))[tid] = bsrc[(tid >> 3) * 1024 + u0 + (tid & 7)];
    if (layer == 0) {
        if (tid < 256) {
            const int kt = tid >> 6, ln = tid & 63;
            const int nn = ln & 15;
            half8 hv;
#pragma unroll
            for (int j = 0; j < 8; ++j) {
                float v = (nn < 8)
                    ? W_h[(size_t)(kt * 32 + (ln >> 4) * 8 + j) * NHID + u0 + nn] : 0.f;
                hv[j] = (_Float16)v;
            }
            *(half8*)(smem + WHF_OFF + kt * 1024 + ln * 16) = hv;
        }
        if (tid < 8) ((float*)(smem + BH_OFF))[tid] = b_h[u0 + tid];
    }
    __syncthreads();

    const float* bg = (const float*)(smem + BIASG_OFF);
    const float* bh = (const float*)(smem + BH_OFF);
    float* zw = (float*)(smem + ZS_OFF + w * 2048);         // [16 rows][32 cols]
    _Float16* hw = (_Float16*)(smem + HS_OFF + w * 256);    // [16 rows][8 u]

    // c state: lane owns (row = n16, units q*2, q*2+1) per mt
    float cst[4][2];
#pragma unroll
    for (int mt = 0; mt < 4; ++mt) { cst[mt][0] = 0.f; cst[mt][1] = 0.f; }

    // ---- proj body (layer-0 WGs): pf(t) -> A1dst low half ----
    auto proj_step = [&](int tstep, _Float16* A1dst) {
        float4v pacc[4];
#pragma unroll
        for (int mt = 0; mt < 4; ++mt) pacc[mt] = (float4v){0.f, 0.f, 0.f, 0.f};
#pragma unroll
        for (int kt = 0; kt < 4; ++kt) {
            half8 B = *(const half8*)(smem + WHF_OFF + kt * 1024 + lane * 16);
#pragma unroll
            for (int mt = 0; mt < 4; ++mt) {
                const int mtg = w * 4 + mt;
                half8 A = *(const half8*)(xf +
                    (((size_t)tstep * 32 + mtg) * 4 + kt) * 512 + lane * 8);
                pacc[mt] = __builtin_amdgcn_mfma_f32_16x16x32_f16(A, B, pacc[mt], 0, 0, 0);
            }
        }
#pragma unroll 1
        for (int mt = 0; mt < 4; ++mt) {
            if (n16 < 8) {
#pragma unroll
                for (int r = 0; r < 4; ++r)
                    zw[(q * 4 + r) * 8 + n16] = pacc[mt][r];
            }
            if (lane < 16) {        // wave-internal LDS: DS ops in-order per wave
                half8 hv;
#pragma unroll
                for (int u = 0; u < 8; ++u)
                    hv[u] = (_Float16)fmaxf(zw[lane * 8 + u] + bh[u], 0.f);
                const int mtg = w * 4 + mt;
                *(half8*)(A1dst + ((size_t)mtg * 64 + (s >> 2)) * 512
                                + ((s & 3) * 16 + lane) * 8) = hv;
            }
        }
    };

    // ---- LSTM GEMM + fused epilogue ----
    auto gemm_step = [&](const _Float16* Asrc, _Float16* hdst1, _Float16* hdst2,
                         float* outp) {
        float4v acc[4][2];
#pragma unroll
        for (int mt = 0; mt < 4; ++mt) {
            acc[mt][0] = (float4v){0.f, 0.f, 0.f, 0.f};
            acc[mt][1] = (float4v){0.f, 0.f, 0.f, 0.f};
        }
        const char* aw[4];
#pragma unroll
        for (int mt = 0; mt < 4; ++mt)
            aw[mt] = (const char*)Asrc + ((size_t)(w * 4 + mt) * 64) * 1024 + lane * 16;

        half8 Ab[2][4];
#pragma unroll
        for (int mt = 0; mt < 4; ++mt) Ab[0][mt] = *(const half8*)(aw[mt]);
#pragma unroll 2
        for (int kt = 0; kt < 64; ++kt) {
            const int cur = kt & 1;
            if (kt < 63) {
#pragma unroll
                for (int mt = 0; mt < 4; ++mt)
                    Ab[cur ^ 1][mt] = *(const half8*)(aw[mt] + (size_t)(kt + 1) * 1024);
            }
            half8 B0 = *(const half8*)(smem + WLDS_OFF + kt * 1024 + lane * 16);
            half8 B1 = *(const half8*)(smem + WLDS_OFF + 65536 + kt * 1024 + lane * 16);
#pragma unroll
            for (int mt = 0; mt < 4; ++mt)
                acc[mt][0] = __builtin_amdgcn_mfma_f32_16x16x32_f16(Ab[cur][mt], B0, acc[mt][0], 0, 0, 0);
#pragma unroll
            for (int mt = 0; mt < 4; ++mt)
                acc[mt][1] = __builtin_amdgcn_mfma_f32_16x16x32_f16(Ab[cur][mt], B1, acc[mt][1], 0, 0, 0);
        }
        // epilogue per mt (cols: g*8+u)
#pragma unroll 1
        for (int mt = 0; mt < 4; ++mt) {
#pragma unroll
            for (int nt = 0; nt < 2; ++nt)
#pragma unroll
                for (int r = 0; r < 4; ++r)
                    zw[(q * 4 + r) * 32 + nt * 16 + n16] = acc[mt][nt][r];
            float hvals[2];
#pragma unroll
            for (int uu = 0; uu < 2; ++uu) {
                const int u = q * 2 + uu;
                const float zi = zw[n16 * 32 +      u] + bg[u];
                const float zj = zw[n16 * 32 +  8 + u] + bg[8 + u];
                const float zf = zw[n16 * 32 + 16 + u] + bg[16 + u];
                const float zo = zw[n16 * 32 + 24 + u] + bg[24 + u];
                float c = cst[mt][uu] * sigmoid_f(zf + 1.0f) + sigmoid_f(zi) * tanh_f(zj);
                cst[mt][uu] = c;
                hvals[uu] = tanh_f(c) * sigmoid_f(zo);
            }
            hw[n16 * 8 + q * 2 + 0] = (_Float16)hvals[0];
            hw[n16 * 8 + q * 2 + 1] = (_Float16)hvals[1];
            if (outp) {
                const int row = (w * 4 + mt) * 16 + n16;
                outp[(size_t)row * NHID + u0 + q * 2 + 0] = hvals[0];
                outp[(size_t)row * NHID + u0 + q * 2 + 1] = hvals[1];
            }
            if (lane < 16) {
                half8 hv = *(half8*)(hw + lane * 8);
                const size_t loff = ((s & 3) * 16 + lane) * 8;
                const int mtg = w * 4 + mt;
                *(half8*)(hdst1 + ((size_t)mtg * 64 + 32 + (s >> 2)) * 512 + loff) = hv;
                if (hdst2)
                    *(half8*)(hdst2 + ((size_t)mtg * 64 + (s >> 2)) * 512 + loff) = hv;
            }
        }
    };

    // ---- pre-phase: proj(0) -> A1[0].low ----
    if (layer == 0) proj_step(0, A1b[0]);
    grid_barrier(cnt, gen, 1u);

    // ---- phases ----
    for (int p = 0; p <= 256; ++p) {
        const int pi = p & 1, po = pi ^ 1;
        if (layer == 0) {
            if (p <= 255)
                gemm_step(A1b[pi], A1b[po], A2b[po], nullptr);   // h1 -> A1hi, A2lo
            if (p + 1 <= 255)
                proj_step(p + 1, A1b[po]);
        } else {
            if (p >= 1)
                gemm_step(A2b[pi], A2b[po], nullptr,
                          (p == 256) ? out : nullptr);           // h2 -> A2hi
        }
        grid_barrier(cnt, gen, (uint32_t)(p + 2));
    }
}

// ---------------------------------------------------------------------------
extern "C" void kernel_launch(void* const* d_in, const int* in_sizes, int n_in,
                              void* d_out, int out_size, void* d_ws, size_t ws_size,
                              hipStream_t stream)
{
    const float* x   = (const float*)d_in[0];
    const float* W_h = (const float*)d_in[1];
    const float* b_h = (const float*)d_in[2];
    const float* k1  = (const float*)d_in[3];
    const float* b1  = (const float*)d_in[4];
    const float* k2  = (const float*)d_in[5];
    const float* b2  = (const float*)d_in[6];
    float* out = (float*)d_out;

    const size_t MB = 1024 * 1024;
    uint8_t* wsb = (uint8_t*)d_ws;
    // A1[0] 0-2, A1[1] 2-4, A2[0] 4-6, A2[1] 6-8 MB ; xf 8-40 MB ; barrier @40 MB
    _Float16* xf = (_Float16*)(wsb + 8 * MB);
    uint32_t* barrier_mem = (uint32_t*)(wsb + 40 * MB);

    hipFuncSetAttribute((const void*)persist_kernel,
                        hipFuncAttributeMaxDynamicSharedMemorySize, SMEM_BYTES);

    hipMemsetAsync(wsb, 0, 8 * MB, stream);          // zero all A-buffers
    hipMemsetAsync(barrier_mem, 0, 4096, stream);
    xconv_kernel<<<dim3(32, 16), 256, 0, stream>>>(x, xf);
    persist_kernel<<<NWGS, 512, SMEM_BYTES, stream>>>(
        k1, b1, k2, b2, W_h, b_h, xf, wsb, out, barrier_mem);
}